// Round 1
// baseline (186.514 us; speedup 1.0000x reference)
//
#include <hip/hip_runtime.h>

#define BB 2
#define SS 2048
#define EE 768
#define HH 12
#define DKK 64

typedef _Float16 h16;
typedef _Float16 half8 __attribute__((ext_vector_type(8)));
typedef float f32x4 __attribute__((ext_vector_type(4)));

// ---------------- mask packing: int32 [S,S] -> 1 bit, word = 32 cols ----------------
__global__ void pack_mask_k(const int* __restrict__ mask, unsigned* __restrict__ mp) {
    int idx = blockIdx.x * 256 + threadIdx.x;      // 0 .. S*S/32-1
    int base = idx * 32;
    const int4* m4 = (const int4*)(mask + base);
    unsigned w = 0;
#pragma unroll
    for (int i = 0; i < 8; ++i) {
        int4 v = m4[i];
        if (v.x) w |= 1u << (i * 4 + 0);
        if (v.y) w |= 1u << (i * 4 + 1);
        if (v.z) w |= 1u << (i * 4 + 2);
        if (v.w) w |= 1u << (i * 4 + 3);
    }
    mp[idx] = w;
}

// ---------------- projection GEMM: dst[b,h,s,d] = (src @ Wk^T + bk), fp16 out ----------------
__launch_bounds__(256)
__global__ void proj_gemm_k(const float* __restrict__ srcK, const float* __restrict__ srcQ,
                            const float* __restrict__ srcV, const float* __restrict__ Wk,
                            const float* __restrict__ bk,
                            h16* __restrict__ kh, h16* __restrict__ qh, h16* __restrict__ vh) {
    __shared__ h16 As[128 * 64];
    __shared__ h16 Bs[128 * 64];
    const int z = blockIdx.z;
    const float* src = (z == 0) ? srcK : ((z == 1) ? srcQ : srcV);
    h16* dst = (z == 0) ? kh : ((z == 1) ? qh : vh);
    const int n0 = blockIdx.x * 128, m0 = blockIdx.y * 128;
    const int tid = threadIdx.x, lane = tid & 63, wid = tid >> 6;
    const int wr = wid >> 1, wc = wid & 1;
    f32x4 acc[4][4] = {};

    for (int k0 = 0; k0 < EE; k0 += 64) {
#pragma unroll
        for (int it = 0; it < 4; ++it) {
            int e8 = it * 256 + tid;          // 0..1023 granules of 8 elems
            int row = e8 >> 3, g = e8 & 7;
            const float* pa = src + (m0 + row) * EE + k0 + g * 8;
            const float* pb = Wk + (n0 + row) * EE + k0 + g * 8;
            float4 a0 = *(const float4*)pa, a1 = *(const float4*)(pa + 4);
            float4 b0 = *(const float4*)pb, b1 = *(const float4*)(pb + 4);
            half8 ha = {(h16)a0.x, (h16)a0.y, (h16)a0.z, (h16)a0.w,
                        (h16)a1.x, (h16)a1.y, (h16)a1.z, (h16)a1.w};
            half8 hb = {(h16)b0.x, (h16)b0.y, (h16)b0.z, (h16)b0.w,
                        (h16)b1.x, (h16)b1.y, (h16)b1.z, (h16)b1.w};
            int sw = (g ^ (row & 7)) << 4;
            *(half8*)((char*)As + row * 128 + sw) = ha;
            *(half8*)((char*)Bs + row * 128 + sw) = hb;
        }
        __syncthreads();
#pragma unroll
        for (int ks = 0; ks < 2; ++ks) {
            half8 a[4], b[4];
#pragma unroll
            for (int rf = 0; rf < 4; ++rf) {
                int row = wr * 64 + rf * 16 + (lane & 15);
                int g = (ks * 4 + (lane >> 4)) ^ (row & 7);
                a[rf] = *(const half8*)((const char*)As + row * 128 + (g << 4));
            }
#pragma unroll
            for (int cf = 0; cf < 4; ++cf) {
                int row = wc * 64 + cf * 16 + (lane & 15);
                int g = (ks * 4 + (lane >> 4)) ^ (row & 7);
                b[cf] = *(const half8*)((const char*)Bs + row * 128 + (g << 4));
            }
#pragma unroll
            for (int rf = 0; rf < 4; ++rf)
#pragma unroll
                for (int cf = 0; cf < 4; ++cf)
                    acc[rf][cf] = __builtin_amdgcn_mfma_f32_16x16x32_f16(a[rf], b[cf], acc[rf][cf], 0, 0, 0);
        }
        __syncthreads();
    }
#pragma unroll
    for (int rf = 0; rf < 4; ++rf)
#pragma unroll
        for (int cf = 0; cf < 4; ++cf) {
            int n = n0 + wc * 64 + cf * 16 + (lane & 15);
            float bias = bk[n];
            int h = n >> 6, d = n & 63;
#pragma unroll
            for (int j = 0; j < 4; ++j) {
                int m = m0 + wr * 64 + rf * 16 + (lane >> 4) * 4 + j;
                int b = m >> 11, s = m & 2047;
                dst[(((b * HH + h) * SS + s) << 6) + d] = (h16)(acc[rf][cf][j] + bias);
            }
        }
}

// ---------------- flash attention over [B,H,S,DK] fp16 q/k/v ----------------
__launch_bounds__(256)
__global__ void attn_k(const h16* __restrict__ qh, const h16* __restrict__ kh,
                       const h16* __restrict__ vh, const unsigned* __restrict__ mp,
                       h16* __restrict__ xh) {
    __shared__ h16 Ks[64 * 64];
    __shared__ h16 Vt[64 * 64];
    __shared__ h16 Ps[4 * 16 * 64];
    __shared__ unsigned Mw[128];
    const int tid = threadIdx.x, lane = tid & 63, wid = tid >> 6;
    const int q0 = blockIdx.x * 64;
    const int bh = blockIdx.y;                 // b*H + h
    const int base = bh * SS * DKK;

    half8 qf[2];
    {
        int row = q0 + wid * 16 + (lane & 15);
        const h16* p = qh + base + row * 64 + (lane >> 4) * 8;
        qf[0] = *(const half8*)p;
        qf[1] = *(const half8*)(p + 32);
    }
    f32x4 o[4] = {};
    float mrow[4], lrow[4];
#pragma unroll
    for (int j = 0; j < 4; ++j) { mrow[j] = -INFINITY; lrow[j] = 0.f; }

    for (int kv0 = 0; kv0 < SS; kv0 += 64) {
        __syncthreads();
        // K tile, row-major [kv][d], swizzled
#pragma unroll
        for (int it = 0; it < 2; ++it) {
            int e8 = it * 256 + tid;
            int c = e8 >> 3, g = e8 & 7;
            half8 kv = *(const half8*)(kh + base + (kv0 + c) * 64 + g * 8);
            *(half8*)((char*)Ks + c * 128 + ((g ^ (c & 7)) << 4)) = kv;
        }
        // V^T tile [d][kv], swizzled (scalar transpose writes)
#pragma unroll
        for (int it = 0; it < 2; ++it) {
            int e8 = it * 256 + tid;
            int kvc = e8 & 63, d0 = (e8 >> 6) * 8;
            half8 vv = *(const half8*)(vh + base + (kv0 + kvc) * 64 + d0);
#pragma unroll
            for (int jj = 0; jj < 8; ++jj) {
                int d = d0 + jj;
                int byt = d * 128 + ((((kvc >> 3) ^ (d & 7))) << 4) + (kvc & 7) * 2;
                *(h16*)((char*)Vt + byt) = vv[jj];
            }
        }
        if (tid < 128) Mw[tid] = mp[(q0 + (tid >> 1)) * (SS / 32) + (kv0 >> 5) + (tid & 1)];
        __syncthreads();

        // S = Q K^T
        f32x4 s[4] = {};
#pragma unroll
        for (int ks = 0; ks < 2; ++ks)
#pragma unroll
            for (int cf = 0; cf < 4; ++cf) {
                int c = cf * 16 + (lane & 15);
                int g = (ks * 4 + (lane >> 4)) ^ (c & 7);
                half8 kf = *(const half8*)((const char*)Ks + c * 128 + (g << 4));
                s[cf] = __builtin_amdgcn_mfma_f32_16x16x32_f16(qf[ks], kf, s[cf], 0, 0, 0);
            }

        // scale*8, mask->1e-6, online softmax
#pragma unroll
        for (int j = 0; j < 4; ++j) {
            int rl = (lane >> 4) * 4 + j;
            unsigned w0 = Mw[(wid * 16 + rl) * 2], w1 = Mw[(wid * 16 + rl) * 2 + 1];
#pragma unroll
            for (int cf = 0; cf < 4; ++cf) {
                int col = cf * 16 + (lane & 15);
                unsigned w = (col & 32) ? w1 : w0;
                bool bit = (w >> (col & 31)) & 1u;
                float sv = s[cf][j];
                s[cf][j] = bit ? sv * 8.0f : 1e-6f;
            }
            float pm = fmaxf(fmaxf(s[0][j], s[1][j]), fmaxf(s[2][j], s[3][j]));
#pragma unroll
            for (int d = 1; d < 16; d <<= 1) pm = fmaxf(pm, __shfl_xor(pm, d));
            float mnew = fmaxf(mrow[j], pm);
            float alpha = __expf(mrow[j] - mnew);
            mrow[j] = mnew;
            float rs = 0.f;
#pragma unroll
            for (int cf = 0; cf < 4; ++cf) {
                float p = __expf(s[cf][j] - mnew);
                s[cf][j] = p;
                rs += p;
            }
#pragma unroll
            for (int d = 1; d < 16; d <<= 1) rs += __shfl_xor(rs, d);
            lrow[j] = lrow[j] * alpha + rs;
#pragma unroll
            for (int cf = 0; cf < 4; ++cf) o[cf][j] *= alpha;
        }

        // P -> LDS (per-wave), swizzled
        char* pbase = (char*)Ps + wid * 2048;
#pragma unroll
        for (int cf = 0; cf < 4; ++cf)
#pragma unroll
            for (int j = 0; j < 4; ++j) {
                int rl = (lane >> 4) * 4 + j;
                int col = cf * 16 + (lane & 15);
                int byt = rl * 128 + ((((col >> 3) ^ (rl & 7))) << 4) + (col & 7) * 2;
                *(h16*)(pbase + byt) = (h16)s[cf][j];
            }
        __syncthreads();

        // O += P V
#pragma unroll
        for (int ks = 0; ks < 2; ++ks) {
            int rl = lane & 15;
            int g = (ks * 4 + (lane >> 4)) ^ (rl & 7);
            half8 pf = *(const half8*)(pbase + rl * 128 + (g << 4));
#pragma unroll
            for (int cf = 0; cf < 4; ++cf) {
                int d = cf * 16 + (lane & 15);
                int gv = (ks * 4 + (lane >> 4)) ^ (d & 7);
                half8 vf = *(const half8*)((const char*)Vt + d * 128 + (gv << 4));
                o[cf] = __builtin_amdgcn_mfma_f32_16x16x32_f16(pf, vf, o[cf], 0, 0, 0);
            }
        }
    }

    // epilogue: x[b,s,h*64+d] fp16
    int b = bh / HH, h = bh % HH;
#pragma unroll
    for (int cf = 0; cf < 4; ++cf)
#pragma unroll
        for (int j = 0; j < 4; ++j) {
            int srow = q0 + wid * 16 + (lane >> 4) * 4 + j;
            int col = h * 64 + cf * 16 + (lane & 15);
            xh[(b * SS + srow) * EE + col] = (h16)(o[cf][j] / lrow[j]);
        }
}

// ---------------- output GEMM: out = x @ Wo^T + bo (fp32 out) ----------------
__launch_bounds__(256)
__global__ void out_gemm_k(const h16* __restrict__ xh, const float* __restrict__ Wo,
                           const float* __restrict__ bo, float* __restrict__ out) {
    __shared__ h16 As[128 * 64];
    __shared__ h16 Bs[128 * 64];
    const int n0 = blockIdx.x * 128, m0 = blockIdx.y * 128;
    const int tid = threadIdx.x, lane = tid & 63, wid = tid >> 6;
    const int wr = wid >> 1, wc = wid & 1;
    f32x4 acc[4][4] = {};

    for (int k0 = 0; k0 < EE; k0 += 64) {
#pragma unroll
        for (int it = 0; it < 4; ++it) {
            int e8 = it * 256 + tid;
            int row = e8 >> 3, g = e8 & 7;
            half8 ha = *(const half8*)(xh + (m0 + row) * EE + k0 + g * 8);
            const float* pb = Wo + (n0 + row) * EE + k0 + g * 8;
            float4 b0 = *(const float4*)pb, b1 = *(const float4*)(pb + 4);
            half8 hb = {(h16)b0.x, (h16)b0.y, (h16)b0.z, (h16)b0.w,
                        (h16)b1.x, (h16)b1.y, (h16)b1.z, (h16)b1.w};
            int sw = (g ^ (row & 7)) << 4;
            *(half8*)((char*)As + row * 128 + sw) = ha;
            *(half8*)((char*)Bs + row * 128 + sw) = hb;
        }
        __syncthreads();
#pragma unroll
        for (int ks = 0; ks < 2; ++ks) {
            half8 a[4], b[4];
#pragma unroll
            for (int rf = 0; rf < 4; ++rf) {
                int row = wr * 64 + rf * 16 + (lane & 15);
                int g = (ks * 4 + (lane >> 4)) ^ (row & 7);
                a[rf] = *(const half8*)((const char*)As + row * 128 + (g << 4));
            }
#pragma unroll
            for (int cf = 0; cf < 4; ++cf) {
                int row = wc * 64 + cf * 16 + (lane & 15);
                int g = (ks * 4 + (lane >> 4)) ^ (row & 7);
                b[cf] = *(const half8*)((const char*)Bs + row * 128 + (g << 4));
            }
#pragma unroll
            for (int rf = 0; rf < 4; ++rf)
#pragma unroll
                for (int cf = 0; cf < 4; ++cf)
                    acc[rf][cf] = __builtin_amdgcn_mfma_f32_16x16x32_f16(a[rf], b[cf], acc[rf][cf], 0, 0, 0);
        }
        __syncthreads();
    }
#pragma unroll
    for (int rf = 0; rf < 4; ++rf)
#pragma unroll
        for (int cf = 0; cf < 4; ++cf) {
            int n = n0 + wc * 64 + cf * 16 + (lane & 15);
            float bias = bo[n];
#pragma unroll
            for (int j = 0; j < 4; ++j) {
                int m = m0 + wr * 64 + rf * 16 + (lane >> 4) * 4 + j;
                out[m * EE + n] = acc[rf][cf][j] + bias;
            }
        }
}

extern "C" void kernel_launch(void* const* d_in, const int* in_sizes, int n_in,
                              void* d_out, int out_size, void* d_ws, size_t ws_size,
                              hipStream_t stream) {
    const float* key   = (const float*)d_in[0];
    const float* query = (const float*)d_in[1];
    const float* value = (const float*)d_in[2];
    const int*   mask  = (const int*)d_in[3];
    const float* Wk    = (const float*)d_in[4];
    const float* bk    = (const float*)d_in[5];
    const float* Wo    = (const float*)d_in[6];
    const float* bo    = (const float*)d_in[7];

    char* ws = (char*)d_ws;
    h16* qh = (h16*)(ws + 0);
    h16* kh = (h16*)(ws + 6291456);
    h16* vh = (h16*)(ws + 12582912);
    h16* xh = (h16*)(ws + 18874368);
    unsigned* mp = (unsigned*)(ws + 25165824);
    float* out = (float*)d_out;

    hipLaunchKernelGGL(pack_mask_k, dim3(SS * SS / 32 / 256), dim3(256), 0, stream, mask, mp);
    hipLaunchKernelGGL(proj_gemm_k, dim3(EE / 128, BB * SS / 128, 3), dim3(256), 0, stream,
                       key, query, value, Wk, bk, kh, qh, vh);
    hipLaunchKernelGGL(attn_k, dim3(SS / 64, BB * HH), dim3(256), 0, stream, qh, kh, vh, mp, xh);
    hipLaunchKernelGGL(out_gemm_k, dim3(EE / 128, BB * SS / 128), dim3(256), 0, stream, xh, Wo, bo, out);
}